// Round 16
// baseline (80.255 us; speedup 1.0000x reference)
//
#include <hip/hip_runtime.h>

#define N_NODES 65536
#define N_EDGES 1048576
#define D 64
#define NB 256                  // major buckets = dst >> 8
#define CHUNK (N_EDGES / NB)    // 4096 edges per passA workgroup
#define SSTAGE 6144             // LDS staging capacity in bucketB
#define FBCAP 65536             // fallback capacity per bucket (ws scratch)

typedef __bf16 bf16x8 __attribute__((ext_vector_type(8)));
typedef float f32x4 __attribute__((ext_vector_type(4)));

__device__ __forceinline__ int edge_at(const void* ei, int is64, long long pos) {
    if (is64) return (int)((const long long*)ei)[pos];
    return ((const int*)ei)[pos];
}

// Inline int64/int32 detection (hi word of int64 indices < 2^17 is always 0).
__device__ __forceinline__ int detect_is64(const unsigned* ei, int* s_is64) {
    if (threadIdx.x < 64) {
        unsigned v = ei[2 * threadIdx.x + 1];
        unsigned long long nz = __ballot(v != 0u);
        if (threadIdx.x == 0) *s_is64 = (nz == 0ull) ? 1 : 0;
    }
    __syncthreads();
    return *s_is64;
}

// ---------------------------------------------------------------------------
// Pass A (round-14 proven): stage chunk in LDS packed (src | dst<<16), LDS
// hist over dst>>8, LDS scan, LDS bucket-sort, coalesced write-out.
// Emits: pairs_cs[w*CHUNK+i], H[b*NB+w] (run length), L[b*NB+w] (run start).
// ---------------------------------------------------------------------------
__global__ __launch_bounds__(256) void passA_kernel(const void* ei,
                                                    unsigned* __restrict__ H,
                                                    unsigned* __restrict__ L,
                                                    unsigned* __restrict__ pairs_cs) {
    __shared__ unsigned ed[CHUNK];
    __shared__ unsigned srt[CHUNK];
    __shared__ unsigned hist[NB];
    __shared__ unsigned scn[NB];
    __shared__ int s_is64;
    const int is64 = detect_is64((const unsigned*)ei, &s_is64);
    const int t = threadIdx.x;
    const int w = blockIdx.x;
    hist[t] = 0;
    __syncthreads();
    const int base = w * CHUNK;
    for (int i = t; i < CHUNK; i += 256) {
        unsigned src = (unsigned)edge_at(ei, is64, base + i);
        unsigned dst = (unsigned)edge_at(ei, is64, (long long)N_EDGES + base + i);
        ed[i] = src | (dst << 16);
        atomicAdd(&hist[dst >> 8], 1u);
    }
    __syncthreads();
    const unsigned own = hist[t];
    scn[t] = own;
    __syncthreads();
    for (int off = 1; off < NB; off <<= 1) {
        unsigned v = (t >= off) ? scn[t - off] : 0u;
        __syncthreads();
        scn[t] += v;
        __syncthreads();
    }
    const unsigned excl = scn[t] - own;
    H[t * NB + w] = own;
    L[t * NB + w] = excl;
    hist[t] = excl;  // reuse as cursor
    __syncthreads();
    for (int i = t; i < CHUNK; i += 256) {
        unsigned p = ed[i];
        unsigned pos = atomicAdd(&hist[p >> 24], 1u);  // bucket = dst>>8 = p>>24
        srt[pos] = p;
    }
    __syncthreads();
    for (int i = t; i < CHUNK; i += 256) pairs_cs[(size_t)w * CHUNK + i] = srt[i];
}

// ---------------------------------------------------------------------------
// Pass B: bucket totals via per-thread H row-sum, LDS scan -> bucket_start;
// FLAT-PARALLEL run-gather: scan run lengths -> s_runoff[257], then each
// thread produces staged element i directly (binary search over s_runoff,
// load from pairs_cs run, sequential LDS write). Then hist over dstlow
// (== deg), LDS scan -> row_start, LDS sort -> coalesced u16 src16.
// y-phase moved out (was latency-bound at 1 block/CU).
// ---------------------------------------------------------------------------
__global__ __launch_bounds__(256) void bucketB_kernel(const unsigned* __restrict__ pairs_cs,
                                                      const unsigned* __restrict__ H,
                                                      const unsigned* __restrict__ L,
                                                      unsigned* __restrict__ row_start,
                                                      unsigned short* __restrict__ src16,
                                                      unsigned* __restrict__ fb) {
    __shared__ unsigned s_pairs[SSTAGE];
    __shared__ unsigned short s_src[SSTAGE];
    __shared__ unsigned hist[NB];
    __shared__ unsigned scn[NB];
    __shared__ unsigned s_tot[NB];
    __shared__ unsigned s_runoff[NB + 1];
    __shared__ unsigned s_Lb[NB];
    const int t = threadIdx.x;
    const int b = blockIdx.x;

    // bucket totals: thread t sums H[t][*] (1 KB contiguous, L2-hit).
    {
        const uint4* Hr = (const uint4*)(H + t * NB);
        unsigned tt = 0;
#pragma unroll 8
        for (int k = 0; k < NB / 4; ++k) {
            uint4 q = Hr[k];
            tt += q.x + q.y + q.z + q.w;
        }
        s_tot[t] = tt;
        scn[t] = tt;
    }
    __syncthreads();
    for (int off = 1; off < NB; off <<= 1) {
        unsigned v = (t >= off) ? scn[t - off] : 0u;
        __syncthreads();
        scn[t] += v;
        __syncthreads();
    }
    const unsigned base = scn[b] - s_tot[b];
    const unsigned cnt = s_tot[b];
    const bool staged = (cnt <= SSTAGE);
    __syncthreads();

    // run-length scan -> s_runoff (exclusive), s_Lb.
    const unsigned Hb = H[b * NB + t];
    s_Lb[t] = L[b * NB + t];
    scn[t] = Hb;
    __syncthreads();
    for (int off = 1; off < NB; off <<= 1) {
        unsigned v = (t >= off) ? scn[t - off] : 0u;
        __syncthreads();
        scn[t] += v;
        __syncthreads();
    }
    s_runoff[t] = scn[t] - Hb;
    if (t == NB - 1) s_runoff[NB] = scn[t];
    __syncthreads();

    // flat-parallel gather: element i <- run w (binary search), offset i-off.
    unsigned* wp = staged ? s_pairs : (fb + (size_t)b * FBCAP);
    for (unsigned i = t; i < cnt; i += 256u) {
        int lo2 = 0, hi2 = NB;
        while (hi2 - lo2 > 1) {
            int mid = (lo2 + hi2) >> 1;
            if (s_runoff[mid] <= i) lo2 = mid; else hi2 = mid;
        }
        wp[i] = pairs_cs[(size_t)lo2 * CHUNK + s_Lb[lo2] + (i - s_runoff[lo2])];
    }
    __syncthreads();
    const unsigned* pp = staged ? s_pairs : (fb + (size_t)b * FBCAP);

    hist[t] = 0;
    __syncthreads();
    for (unsigned i = t; i < cnt; i += 256u) {
        atomicAdd(&hist[(pp[i] >> 16) & 255u], 1u);
    }
    __syncthreads();
    const unsigned own = hist[t];
    scn[t] = own;
    __syncthreads();
    for (int off = 1; off < NB; off <<= 1) {
        unsigned v = (t >= off) ? scn[t - off] : 0u;
        __syncthreads();
        scn[t] += v;
        __syncthreads();
    }
    const unsigned excl = scn[t] - own;
    row_start[b * NB + t] = base + excl;
    if (b == NB - 1 && t == 0) row_start[N_NODES] = N_EDGES;
    hist[t] = excl;  // reuse as cursor
    __syncthreads();
    if (staged) {
        for (unsigned i = t; i < cnt; i += 256u) {
            unsigned p = pp[i];
            unsigned pos = atomicAdd(&hist[(p >> 16) & 255u], 1u);
            s_src[pos] = (unsigned short)(p & 0xFFFFu);
        }
        __syncthreads();
        for (unsigned i = t; i < cnt; i += 256u) src16[base + i] = s_src[i];
    } else {  // statistically unreachable
        for (unsigned i = t; i < cnt; i += 256u) {
            unsigned p = pp[i];
            unsigned pos = atomicAdd(&hist[(p >> 16) & 255u], 1u);
            src16[base + pos] = (unsigned short)(p & 0xFFFFu);
        }
    }
}

// ---------------------------------------------------------------------------
// y[n][d] = bf16(rsqrt(deg[n]) * x[n][d]); deg from row_start (L2-warm).
// High-occupancy streaming kernel (8192 blocks) — runs at HBM BW.
// ---------------------------------------------------------------------------
__global__ __launch_bounds__(256) void y_kernel(const float* __restrict__ x,
                                                const unsigned* __restrict__ row_start,
                                                unsigned* __restrict__ y32) {
    int idx = blockIdx.x * blockDim.x + threadIdx.x;  // 0 .. N_NODES*32
    int n = idx >> 5;
    int col = idx & 31;
    unsigned d = row_start[n + 1] - row_start[n];
    float w = d ? rsqrtf((float)d) : 0.f;
    float2 v = *(const float2*)(x + n * D + col * 2);
    unsigned lo = (unsigned)__builtin_bit_cast(unsigned short, (__bf16)(v.x * w));
    unsigned hi = (unsigned)__builtin_bit_cast(unsigned short, (__bf16)(v.y * w));
    y32[idx] = lo | (hi << 16);
}

// ---------------------------------------------------------------------------
// Atomic-free segmented SpMM, NO cross-lane reduction (round-13 proven).
// Wave = 8 nodes x 8 lanes: group g owns node nb+g, lane r8 owns feature
// chunk [8*r8, 8*r8+8); serial edge walk, unroll-4. Store = one coalesced
// 1 KB line per wave.
// ---------------------------------------------------------------------------
#define BLO(u) __uint_as_float((u) << 16)
#define BHI(u) __uint_as_float((u) & 0xffff0000u)
__device__ __forceinline__ unsigned pkbf(float lo, float hi) {
    return (unsigned)__builtin_bit_cast(unsigned short, (__bf16)lo) |
           ((unsigned)__builtin_bit_cast(unsigned short, (__bf16)hi) << 16);
}
__device__ __forceinline__ void acc8(uint4 p, float* a) {
    a[0] += BLO(p.x); a[1] += BHI(p.x);
    a[2] += BLO(p.y); a[3] += BHI(p.y);
    a[4] += BLO(p.z); a[5] += BHI(p.z);
    a[6] += BLO(p.w); a[7] += BHI(p.w);
}
__global__ __launch_bounds__(256) void spmm_kernel(const unsigned short* __restrict__ src16,
                                                   const unsigned* __restrict__ row_start,
                                                   const uint4* __restrict__ y128,
                                                   uint4* __restrict__ hb4) {
    const int lane = threadIdx.x & 63;
    const int g = lane >> 3;     // node slot 0..7
    const int r8 = lane & 7;     // feature chunk [8*r8, 8*r8+8)
    int wv = (blockIdx.x * blockDim.x + threadIdx.x) >> 6;
    int nwv = (gridDim.x * blockDim.x) >> 6;
    for (int nb = wv * 8; nb < N_NODES; nb += nwv * 8) {
        const int n = nb + g;
        const unsigned start = row_start[n];
        const unsigned end = row_start[n + 1];
        float a[8] = {0.f, 0.f, 0.f, 0.f, 0.f, 0.f, 0.f, 0.f};
        float c[8] = {0.f, 0.f, 0.f, 0.f, 0.f, 0.f, 0.f, 0.f};
        unsigned i = start;
        for (; i + 4 <= end; i += 4) {
            int s0 = (int)src16[i];
            int s1 = (int)src16[i + 1];
            int s2 = (int)src16[i + 2];
            int s3 = (int)src16[i + 3];
            uint4 p0 = y128[s0 * 8 + r8];
            uint4 p1 = y128[s1 * 8 + r8];
            uint4 p2 = y128[s2 * 8 + r8];
            uint4 p3 = y128[s3 * 8 + r8];
            acc8(p0, a); acc8(p1, c);
            acc8(p2, a); acc8(p3, c);
        }
        for (; i < end; ++i) {
            uint4 p = y128[(int)src16[i] * 8 + r8];
            acc8(p, a);
        }
        const float w = (end > start) ? rsqrtf((float)(end - start)) : 0.f;
        uint4 v;
        v.x = pkbf((a[0] + c[0]) * w, (a[1] + c[1]) * w);
        v.y = pkbf((a[2] + c[2]) * w, (a[3] + c[3]) * w);
        v.z = pkbf((a[4] + c[4]) * w, (a[5] + c[5]) * w);
        v.w = pkbf((a[6] + c[6]) * w, (a[7] + c[7]) * w);
        hb4[(size_t)nb * 8 + lane] = v;  // n*8 + r8 == nb*8 + lane
    }
}

// ---------------------------------------------------------------------------
// out = leaky(h@W1+b1) + leaky((x*h)@W2+b2) via mfma_f32_16x16x32_bf16.
// x is NOT read: x~ = y * sqrt(deg) (cache-warm). deg from row_start.
// ---------------------------------------------------------------------------
__global__ __launch_bounds__(256) void dense_mfma_kernel(const uint4* __restrict__ y128,
                                                         const uint4* __restrict__ hb4,
                                                         const unsigned* __restrict__ row_start,
                                                         const float* __restrict__ W1,
                                                         const float* __restrict__ b1,
                                                         const float* __restrict__ W2,
                                                         const float* __restrict__ b2,
                                                         float* __restrict__ out) {
    const int lane = threadIdx.x & 63;
    const int lo = lane & 15;
    const int hi = lane >> 4;

    bf16x8 bw1[2][4], bw2[2][4];
#pragma unroll
    for (int kt = 0; kt < 2; ++kt)
#pragma unroll
        for (int nt = 0; nt < 4; ++nt) {
            bf16x8 v1, v2;
#pragma unroll
            for (int j = 0; j < 8; ++j) {
                int k = kt * 32 + hi * 8 + j;
                int n = nt * 16 + lo;
                v1[j] = (__bf16)W1[k * D + n];
                v2[j] = (__bf16)W2[k * D + n];
            }
            bw1[kt][nt] = v1;
            bw2[kt][nt] = v2;
        }
    float bb1[4], bb2[4];
#pragma unroll
    for (int nt = 0; nt < 4; ++nt) {
        bb1[nt] = b1[nt * 16 + lo];
        bb2[nt] = b2[nt * 16 + lo];
    }

    int wid = (blockIdx.x * blockDim.x + threadIdx.x) >> 6;
    int nw = (gridDim.x * blockDim.x) >> 6;
    for (int blk = wid; blk < N_NODES / 16; blk += nw) {
        const int rb = blk * 16;
        const int row = rb + lo;
        const uint4* hrow = hb4 + (size_t)row * 8;
        const uint4* yrow = y128 + (size_t)row * 8;
        const float sd = sqrtf((float)(row_start[row + 1] - row_start[row]));
        bf16x8 ah[2], ag[2];
#pragma unroll
        for (int kt = 0; kt < 2; ++kt) {
            uint4 hp = hrow[kt * 4 + hi];
            uint4 yp = yrow[kt * 4 + hi];
            ah[kt] = __builtin_bit_cast(bf16x8, hp);
            bf16x8 g;
            g[0] = (__bf16)(BLO(hp.x) * (BLO(yp.x) * sd));
            g[1] = (__bf16)(BHI(hp.x) * (BHI(yp.x) * sd));
            g[2] = (__bf16)(BLO(hp.y) * (BLO(yp.y) * sd));
            g[3] = (__bf16)(BHI(hp.y) * (BHI(yp.y) * sd));
            g[4] = (__bf16)(BLO(hp.z) * (BLO(yp.z) * sd));
            g[5] = (__bf16)(BHI(hp.z) * (BHI(yp.z) * sd));
            g[6] = (__bf16)(BLO(hp.w) * (BLO(yp.w) * sd));
            g[7] = (__bf16)(BHI(hp.w) * (BHI(yp.w) * sd));
            ag[kt] = g;
        }
        f32x4 acc1[4], acc2[4];
#pragma unroll
        for (int nt = 0; nt < 4; ++nt) {
            acc1[nt] = (f32x4){0.f, 0.f, 0.f, 0.f};
            acc2[nt] = (f32x4){0.f, 0.f, 0.f, 0.f};
        }
#pragma unroll
        for (int kt = 0; kt < 2; ++kt)
#pragma unroll
            for (int nt = 0; nt < 4; ++nt) {
                acc1[nt] = __builtin_amdgcn_mfma_f32_16x16x32_bf16(ah[kt], bw1[kt][nt], acc1[nt], 0, 0, 0);
                acc2[nt] = __builtin_amdgcn_mfma_f32_16x16x32_bf16(ag[kt], bw2[kt][nt], acc2[nt], 0, 0, 0);
            }
#pragma unroll
        for (int nt = 0; nt < 4; ++nt)
#pragma unroll
            for (int r = 0; r < 4; ++r) {
                float a1 = acc1[nt][r] + bb1[nt];
                float a2 = acc2[nt][r] + bb2[nt];
                a1 = (a1 >= 0.f) ? a1 : 0.2f * a1;
                a2 = (a2 >= 0.f) ? a2 : 0.2f * a2;
                out[(rb + hi * 4 + r) * D + nt * 16 + lo] = a1 + a2;
            }
    }
}

extern "C" void kernel_launch(void* const* d_in, const int* in_sizes, int n_in,
                              void* d_out, int out_size, void* d_ws, size_t ws_size,
                              hipStream_t stream) {
    const float* x  = (const float*)d_in[0];
    const void*  ei = d_in[1];
    const float* W1 = (const float*)d_in[2];
    const float* b1 = (const float*)d_in[3];
    const float* W2 = (const float*)d_in[4];
    const float* b2 = (const float*)d_in[5];
    float* out = (float*)d_out;

    char* p = (char*)d_ws;
    unsigned* row_start    = (unsigned*)p;       p += 266240;          // 65537 u32
    unsigned* H            = (unsigned*)p;       p += NB * NB * 4;     // 256 KB
    unsigned* L            = (unsigned*)p;       p += NB * NB * 4;     // 256 KB
    unsigned short* src16  = (unsigned short*)p; p += (size_t)N_EDGES * 2;      // 2 MB
    unsigned* y32          = (unsigned*)p;       p += (size_t)N_NODES * 32 * 4; // 8 MB
    unsigned* hb           = (unsigned*)p;       p += (size_t)N_NODES * 32 * 4; // 8 MB
    unsigned* fb           = (unsigned*)p;       // 64 MB fallback (rarely touched)

    // pairs_cs scratch lives in d_out: written by passA, consumed by bucketB,
    // then d_out is fully overwritten by dense_mfma. Deterministic modulo
    // intra-run LDS-atomic order (rounding-level only, as in prior rounds).
    unsigned* pairs_cs = (unsigned*)d_out;

    passA_kernel<<<NB, 256, 0, stream>>>(ei, H, L, pairs_cs);
    bucketB_kernel<<<NB, 256, 0, stream>>>(pairs_cs, H, L, row_start, src16, fb);
    y_kernel<<<N_NODES * 32 / 256, 256, 0, stream>>>(x, row_start, y32);
    spmm_kernel<<<2048, 256, 0, stream>>>(src16, row_start, (const uint4*)y32, (uint4*)hb);
    dense_mfma_kernel<<<1024, 256, 0, stream>>>((const uint4*)y32, (const uint4*)hb,
                                                row_start, W1, b1, W2, b2, out);
}

// Round 17
// 71.950 us; speedup vs baseline: 1.1154x; 1.1154x over previous
//
#include <hip/hip_runtime.h>

#define N_NODES 65536
#define N_EDGES 1048576
#define D 64
#define NB 256                  // major buckets = dst >> 8
#define CHUNK (N_EDGES / NB)    // 4096 edges per passA workgroup
#define SSTAGE 6144             // LDS staging capacity in bucketB
#define FBCAP 65536             // fallback capacity per bucket (ws scratch)

typedef __bf16 bf16x8 __attribute__((ext_vector_type(8)));
typedef float f32x4 __attribute__((ext_vector_type(4)));

__device__ __forceinline__ int edge_at(const void* ei, int is64, long long pos) {
    if (is64) return (int)((const long long*)ei)[pos];
    return ((const int*)ei)[pos];
}

// Inline int64/int32 detection (hi word of int64 indices < 2^17 is always 0).
__device__ __forceinline__ int detect_is64(const unsigned* ei, int* s_is64) {
    if (threadIdx.x < 64) {
        unsigned v = ei[2 * threadIdx.x + 1];
        unsigned long long nz = __ballot(v != 0u);
        if (threadIdx.x == 0) *s_is64 = (nz == 0ull) ? 1 : 0;
    }
    __syncthreads();
    return *s_is64;
}

// ---------------------------------------------------------------------------
// Pass A: stage chunk in LDS packed (src | dst<<16), LDS hist over dst>>8,
// LDS scan, LDS bucket-sort, coalesced write-out.
// Emits: pairs_cs[w*CHUNK + i], H[b*NB+w] (run length), L[b*NB+w] (run start).
// ---------------------------------------------------------------------------
__global__ __launch_bounds__(256) void passA_kernel(const void* ei,
                                                    unsigned* __restrict__ H,
                                                    unsigned* __restrict__ L,
                                                    unsigned* __restrict__ pairs_cs) {
    __shared__ unsigned ed[CHUNK];
    __shared__ unsigned srt[CHUNK];
    __shared__ unsigned hist[NB];
    __shared__ unsigned scn[NB];
    __shared__ int s_is64;
    const int is64 = detect_is64((const unsigned*)ei, &s_is64);
    const int t = threadIdx.x;
    const int w = blockIdx.x;
    hist[t] = 0;
    __syncthreads();
    const int base = w * CHUNK;
    for (int i = t; i < CHUNK; i += 256) {
        unsigned src = (unsigned)edge_at(ei, is64, base + i);
        unsigned dst = (unsigned)edge_at(ei, is64, (long long)N_EDGES + base + i);
        ed[i] = src | (dst << 16);
        atomicAdd(&hist[dst >> 8], 1u);
    }
    __syncthreads();
    const unsigned own = hist[t];
    scn[t] = own;
    __syncthreads();
    for (int off = 1; off < NB; off <<= 1) {
        unsigned v = (t >= off) ? scn[t - off] : 0u;
        __syncthreads();
        scn[t] += v;
        __syncthreads();
    }
    const unsigned excl = scn[t] - own;
    H[t * NB + w] = own;
    L[t * NB + w] = excl;
    hist[t] = excl;  // reuse as cursor
    __syncthreads();
    for (int i = t; i < CHUNK; i += 256) {
        unsigned p = ed[i];
        unsigned pos = atomicAdd(&hist[p >> 24], 1u);  // bucket = dst>>8 = p>>24
        srt[pos] = p;
    }
    __syncthreads();
    for (int i = t; i < CHUNK; i += 256) pairs_cs[(size_t)w * CHUNK + i] = srt[i];
}

// ---------------------------------------------------------------------------
// Pass B (round-14 structure): bucket totals via per-thread H row-sum, LDS
// scan -> bucket_start; run-gather (thread t copies chunk t's run, 4 loads
// in flight); hist over dstlow (== deg), LDS scan -> row_start, LDS sort ->
// coalesced u16 src16, prefolded bf16 y.
// ---------------------------------------------------------------------------
__global__ __launch_bounds__(256) void bucketB_kernel(const unsigned* __restrict__ pairs_cs,
                                                      const unsigned* __restrict__ H,
                                                      const unsigned* __restrict__ L,
                                                      const float* __restrict__ x,
                                                      unsigned* __restrict__ row_start,
                                                      unsigned short* __restrict__ src16,
                                                      unsigned* __restrict__ y32,
                                                      unsigned* __restrict__ fb) {
    __shared__ unsigned s_pairs[SSTAGE];
    __shared__ unsigned short s_src[SSTAGE];
    __shared__ unsigned hist[NB];
    __shared__ unsigned scn[NB];
    __shared__ unsigned degs[NB];
    __shared__ unsigned s_tot[NB];
    const int t = threadIdx.x;
    const int b = blockIdx.x;

    // bucket totals: thread t sums H[t][*] (1 KB contiguous, L2-hit).
    {
        const uint4* Hr = (const uint4*)(H + t * NB);
        unsigned tt = 0;
#pragma unroll 8
        for (int k = 0; k < NB / 4; ++k) {
            uint4 q = Hr[k];
            tt += q.x + q.y + q.z + q.w;
        }
        s_tot[t] = tt;
        scn[t] = tt;
    }
    __syncthreads();
    for (int off = 1; off < NB; off <<= 1) {
        unsigned v = (t >= off) ? scn[t - off] : 0u;
        __syncthreads();
        scn[t] += v;
        __syncthreads();
    }
    const unsigned base = scn[b] - s_tot[b];
    const unsigned cnt = s_tot[b];
    const bool staged = (cnt <= SSTAGE);
    __syncthreads();

    // run-gather: thread t copies chunk t's run, 4 independent loads/iter.
    const unsigned Hb = H[b * NB + t];
    const unsigned Lb = L[b * NB + t];
    scn[t] = Hb;
    __syncthreads();
    for (int off = 1; off < NB; off <<= 1) {
        unsigned v = (t >= off) ? scn[t - off] : 0u;
        __syncthreads();
        scn[t] += v;
        __syncthreads();
    }
    const unsigned ex = scn[t] - Hb;
    unsigned* wp = staged ? s_pairs : (fb + (size_t)b * FBCAP);
    {
        const unsigned* rp = pairs_cs + (size_t)t * CHUNK + Lb;
        unsigned j = 0;
        for (; j + 4 <= Hb; j += 4) {
            unsigned v0 = rp[j], v1 = rp[j + 1], v2 = rp[j + 2], v3 = rp[j + 3];
            wp[ex + j] = v0; wp[ex + j + 1] = v1;
            wp[ex + j + 2] = v2; wp[ex + j + 3] = v3;
        }
        for (; j < Hb; ++j) wp[ex + j] = rp[j];
    }
    __syncthreads();
    const unsigned* pp = staged ? s_pairs : (fb + (size_t)b * FBCAP);

    hist[t] = 0;
    __syncthreads();
    for (unsigned i = t; i < cnt; i += 256u) {
        atomicAdd(&hist[(pp[i] >> 16) & 255u], 1u);
    }
    __syncthreads();
    const unsigned own = hist[t];
    degs[t] = own;
    scn[t] = own;
    __syncthreads();
    for (int off = 1; off < NB; off <<= 1) {
        unsigned v = (t >= off) ? scn[t - off] : 0u;
        __syncthreads();
        scn[t] += v;
        __syncthreads();
    }
    const unsigned excl = scn[t] - own;
    row_start[b * NB + t] = base + excl;
    if (b == NB - 1 && t == 0) row_start[N_NODES] = N_EDGES;
    hist[t] = excl;  // reuse as cursor
    __syncthreads();
    if (staged) {
        for (unsigned i = t; i < cnt; i += 256u) {
            unsigned p = pp[i];
            unsigned pos = atomicAdd(&hist[(p >> 16) & 255u], 1u);
            s_src[pos] = (unsigned short)(p & 0xFFFFu);
        }
        __syncthreads();
        for (unsigned i = t; i < cnt; i += 256u) src16[base + i] = s_src[i];
    } else {  // statistically unreachable
        for (unsigned i = t; i < cnt; i += 256u) {
            unsigned p = pp[i];
            unsigned pos = atomicAdd(&hist[(p >> 16) & 255u], 1u);
            src16[base + pos] = (unsigned short)(p & 0xFFFFu);
        }
    }
    // y phase: y[n][d] = bf16(rsqrt(deg[n]) * x[n][d]), unified layout.
    const int nbase = b * NB;
    for (int idx = t; idx < NB * 32; idx += 256) {
        int nl = idx >> 5;
        int col = idx & 31;               // u32 column (2 feats each)
        unsigned d = degs[nl];
        float w = d ? rsqrtf((float)d) : 0.f;
        float2 v = *(const float2*)(x + (nbase + nl) * D + col * 2);
        unsigned lo = (unsigned)__builtin_bit_cast(unsigned short, (__bf16)(v.x * w));
        unsigned hi = (unsigned)__builtin_bit_cast(unsigned short, (__bf16)(v.y * w));
        y32[(size_t)(nbase + nl) * 32 + col] = lo | (hi << 16);
    }
}

// ---------------------------------------------------------------------------
// Atomic-free segmented SpMM, NO cross-lane reduction (round-13 proven).
// Wave = 8 nodes x 8 lanes: group g owns node nb+g, lane r8 owns feature
// chunk [8*r8, 8*r8+8); serial edge walk, unroll-4. Store = one coalesced
// 1 KB line per wave.
// ---------------------------------------------------------------------------
#define BLO(u) __uint_as_float((u) << 16)
#define BHI(u) __uint_as_float((u) & 0xffff0000u)
__device__ __forceinline__ unsigned pkbf(float lo, float hi) {
    return (unsigned)__builtin_bit_cast(unsigned short, (__bf16)lo) |
           ((unsigned)__builtin_bit_cast(unsigned short, (__bf16)hi) << 16);
}
__device__ __forceinline__ void acc8(uint4 p, float* a) {
    a[0] += BLO(p.x); a[1] += BHI(p.x);
    a[2] += BLO(p.y); a[3] += BHI(p.y);
    a[4] += BLO(p.z); a[5] += BHI(p.z);
    a[6] += BLO(p.w); a[7] += BHI(p.w);
}
__global__ __launch_bounds__(256) void spmm_kernel(const unsigned short* __restrict__ src16,
                                                   const unsigned* __restrict__ row_start,
                                                   const uint4* __restrict__ y128,
                                                   uint4* __restrict__ hb4) {
    const int lane = threadIdx.x & 63;
    const int g = lane >> 3;     // node slot 0..7
    const int r8 = lane & 7;     // feature chunk [8*r8, 8*r8+8)
    int wv = (blockIdx.x * blockDim.x + threadIdx.x) >> 6;
    int nwv = (gridDim.x * blockDim.x) >> 6;
    for (int nb = wv * 8; nb < N_NODES; nb += nwv * 8) {
        const int n = nb + g;
        const unsigned start = row_start[n];
        const unsigned end = row_start[n + 1];
        float a[8] = {0.f, 0.f, 0.f, 0.f, 0.f, 0.f, 0.f, 0.f};
        float c[8] = {0.f, 0.f, 0.f, 0.f, 0.f, 0.f, 0.f, 0.f};
        unsigned i = start;
        for (; i + 4 <= end; i += 4) {
            int s0 = (int)src16[i];
            int s1 = (int)src16[i + 1];
            int s2 = (int)src16[i + 2];
            int s3 = (int)src16[i + 3];
            uint4 p0 = y128[s0 * 8 + r8];
            uint4 p1 = y128[s1 * 8 + r8];
            uint4 p2 = y128[s2 * 8 + r8];
            uint4 p3 = y128[s3 * 8 + r8];
            acc8(p0, a); acc8(p1, c);
            acc8(p2, a); acc8(p3, c);
        }
        for (; i < end; ++i) {
            uint4 p = y128[(int)src16[i] * 8 + r8];
            acc8(p, a);
        }
        const float w = (end > start) ? rsqrtf((float)(end - start)) : 0.f;
        uint4 v;
        v.x = pkbf((a[0] + c[0]) * w, (a[1] + c[1]) * w);
        v.y = pkbf((a[2] + c[2]) * w, (a[3] + c[3]) * w);
        v.z = pkbf((a[4] + c[4]) * w, (a[5] + c[5]) * w);
        v.w = pkbf((a[6] + c[6]) * w, (a[7] + c[7]) * w);
        hb4[(size_t)nb * 8 + lane] = v;  // n*8 + r8 == nb*8 + lane
    }
}

// ---------------------------------------------------------------------------
// out = leaky(h@W1+b1) + leaky((x*h)@W2+b2) via mfma_f32_16x16x32_bf16.
// x is NOT read: x~ = y * sqrt(deg) (y is bf16 of rsqrt(deg)*x; cache-warm
// from spmm). Zero-deg rows: y=0 & h=0 -> g=0, exact. deg from row_start.
// ---------------------------------------------------------------------------
__global__ __launch_bounds__(256) void dense_mfma_kernel(const uint4* __restrict__ y128,
                                                         const uint4* __restrict__ hb4,
                                                         const unsigned* __restrict__ row_start,
                                                         const float* __restrict__ W1,
                                                         const float* __restrict__ b1,
                                                         const float* __restrict__ W2,
                                                         const float* __restrict__ b2,
                                                         float* __restrict__ out) {
    const int lane = threadIdx.x & 63;
    const int lo = lane & 15;
    const int hi = lane >> 4;

    bf16x8 bw1[2][4], bw2[2][4];
#pragma unroll
    for (int kt = 0; kt < 2; ++kt)
#pragma unroll
        for (int nt = 0; nt < 4; ++nt) {
            bf16x8 v1, v2;
#pragma unroll
            for (int j = 0; j < 8; ++j) {
                int k = kt * 32 + hi * 8 + j;
                int n = nt * 16 + lo;
                v1[j] = (__bf16)W1[k * D + n];
                v2[j] = (__bf16)W2[k * D + n];
            }
            bw1[kt][nt] = v1;
            bw2[kt][nt] = v2;
        }
    float bb1[4], bb2[4];
#pragma unroll
    for (int nt = 0; nt < 4; ++nt) {
        bb1[nt] = b1[nt * 16 + lo];
        bb2[nt] = b2[nt * 16 + lo];
    }

    int wid = (blockIdx.x * blockDim.x + threadIdx.x) >> 6;
    int nw = (gridDim.x * blockDim.x) >> 6;
    for (int blk = wid; blk < N_NODES / 16; blk += nw) {
        const int rb = blk * 16;
        const int row = rb + lo;
        const uint4* hrow = hb4 + (size_t)row * 8;
        const uint4* yrow = y128 + (size_t)row * 8;
        const float sd = sqrtf((float)(row_start[row + 1] - row_start[row]));
        bf16x8 ah[2], ag[2];
#pragma unroll
        for (int kt = 0; kt < 2; ++kt) {
            uint4 hp = hrow[kt * 4 + hi];
            uint4 yp = yrow[kt * 4 + hi];
            ah[kt] = __builtin_bit_cast(bf16x8, hp);
            bf16x8 g;
            g[0] = (__bf16)(BLO(hp.x) * (BLO(yp.x) * sd));
            g[1] = (__bf16)(BHI(hp.x) * (BHI(yp.x) * sd));
            g[2] = (__bf16)(BLO(hp.y) * (BLO(yp.y) * sd));
            g[3] = (__bf16)(BHI(hp.y) * (BHI(yp.y) * sd));
            g[4] = (__bf16)(BLO(hp.z) * (BLO(yp.z) * sd));
            g[5] = (__bf16)(BHI(hp.z) * (BHI(yp.z) * sd));
            g[6] = (__bf16)(BLO(hp.w) * (BLO(yp.w) * sd));
            g[7] = (__bf16)(BHI(hp.w) * (BHI(yp.w) * sd));
            ag[kt] = g;
        }
        f32x4 acc1[4], acc2[4];
#pragma unroll
        for (int nt = 0; nt < 4; ++nt) {
            acc1[nt] = (f32x4){0.f, 0.f, 0.f, 0.f};
            acc2[nt] = (f32x4){0.f, 0.f, 0.f, 0.f};
        }
#pragma unroll
        for (int kt = 0; kt < 2; ++kt)
#pragma unroll
            for (int nt = 0; nt < 4; ++nt) {
                acc1[nt] = __builtin_amdgcn_mfma_f32_16x16x32_bf16(ah[kt], bw1[kt][nt], acc1[nt], 0, 0, 0);
                acc2[nt] = __builtin_amdgcn_mfma_f32_16x16x32_bf16(ag[kt], bw2[kt][nt], acc2[nt], 0, 0, 0);
            }
#pragma unroll
        for (int nt = 0; nt < 4; ++nt)
#pragma unroll
            for (int r = 0; r < 4; ++r) {
                float a1 = acc1[nt][r] + bb1[nt];
                float a2 = acc2[nt][r] + bb2[nt];
                a1 = (a1 >= 0.f) ? a1 : 0.2f * a1;
                a2 = (a2 >= 0.f) ? a2 : 0.2f * a2;
                out[(rb + hi * 4 + r) * D + nt * 16 + lo] = a1 + a2;
            }
    }
}

extern "C" void kernel_launch(void* const* d_in, const int* in_sizes, int n_in,
                              void* d_out, int out_size, void* d_ws, size_t ws_size,
                              hipStream_t stream) {
    const float* x  = (const float*)d_in[0];
    const void*  ei = d_in[1];
    const float* W1 = (const float*)d_in[2];
    const float* b1 = (const float*)d_in[3];
    const float* W2 = (const float*)d_in[4];
    const float* b2 = (const float*)d_in[5];
    float* out = (float*)d_out;

    char* p = (char*)d_ws;
    unsigned* row_start    = (unsigned*)p;       p += 266240;          // 65537 u32
    unsigned* H            = (unsigned*)p;       p += NB * NB * 4;     // 256 KB
    unsigned* L            = (unsigned*)p;       p += NB * NB * 4;     // 256 KB
    unsigned short* src16  = (unsigned short*)p; p += (size_t)N_EDGES * 2;      // 2 MB
    unsigned* y32          = (unsigned*)p;       p += (size_t)N_NODES * 32 * 4; // 8 MB
    unsigned* hb           = (unsigned*)p;       p += (size_t)N_NODES * 32 * 4; // 8 MB
    unsigned* fb           = (unsigned*)p;       // 64 MB fallback (rarely touched)

    // pairs_cs scratch lives in d_out: written by passA, consumed by bucketB,
    // then d_out is fully overwritten by dense_mfma. Deterministic modulo
    // intra-run LDS-atomic order (rounding-level only, as in prior rounds).
    unsigned* pairs_cs = (unsigned*)d_out;

    passA_kernel<<<NB, 256, 0, stream>>>(ei, H, L, pairs_cs);
    bucketB_kernel<<<NB, 256, 0, stream>>>(pairs_cs, H, L, x, row_start, src16, y32, fb);
    spmm_kernel<<<2048, 256, 0, stream>>>(src16, row_start, (const uint4*)y32, (uint4*)hb);
    dense_mfma_kernel<<<1024, 256, 0, stream>>>((const uint4*)y32, (const uint4*)hb,
                                                row_start, W1, b1, W2, b2, out);
}